// Round 7
// baseline (150.135 us; speedup 1.0000x reference)
//
#include <hip/hip_runtime.h>
#include <hip/hip_bf16.h>

#define SEQ 4096
#define MTOT 16384

typedef float f32x4  __attribute__((ext_vector_type(4)));
typedef float f32x16 __attribute__((ext_vector_type(16)));
typedef _Float16 f16;
typedef _Float16 f16x4 __attribute__((ext_vector_type(4)));
typedef _Float16 f16x8 __attribute__((ext_vector_type(8)));
typedef unsigned int   u32;
typedef unsigned int   u32x2 __attribute__((ext_vector_type(2)));
typedef unsigned short u16;

// ws byte offsets
static constexpr size_t QS_B  = 0;          // fp16 Q (pre-scaled) [16384][64]        2MB
static constexpr size_t KS_B  = 2u << 20;   // fp16 K [16384][64]                     2MB
static constexpr size_t VT_B  = 4u << 20;   // fp16 V^T tiled [4][128tile][64d][32kv] 2MB
static constexpr size_t W16_B = 6u << 20;   // fp16 W [192][512] (Wq scaled)        192KB

__device__ __forceinline__ u16 h16(float v) { return __builtin_bit_cast(u16, (f16)v); }
__device__ __forceinline__ u32 pkrtz(float a, float b) {
  return __builtin_bit_cast(u32, __builtin_amdgcn_cvt_pkrtz(a, b));
}

// ---------------- W fp32 -> fp16 (Wq folded with 0.125*log2e) ----------------
__global__ __launch_bounds__(256) void wconv_kernel(const float* __restrict__ Wq,
                                                    const float* __restrict__ Wk,
                                                    const float* __restrict__ Wv,
                                                    u16* __restrict__ w16) {
  const float QSC = 0.18033688011112042f;  // 0.125 * log2(e)
  int e = (blockIdx.x * 256 + threadIdx.x) * 4;  // [0, 98304)
  int mat = e >> 15;
  const float* W = (mat == 0) ? Wq : (mat == 1 ? Wk : Wv);
  f32x4 v = *(const f32x4*)(W + (e & 32767));
  if (mat == 0) v *= QSC;
  __attribute__((aligned(8))) u16 b[4];
#pragma unroll
  for (int j = 0; j < 4; ++j) b[j] = h16(v[j]);
  *(uint2*)(w16 + e) = *(uint2*)b;
}

// ---------------- QKV projection ----------------
// 1024 blocks x 256 thr (4 waves, 4 blocks/CU). Block: 16 x-rows; wave ng: cols ng*48..+47
// (3 subtiles of 16). K=512 in 16 steps of 32. Fragments direct from global.
__global__ __launch_bounds__(256, 4) void proj_kernel(const float* __restrict__ x,
                                                      const u16* __restrict__ w16,
                                                      u16* __restrict__ ws) {
  __shared__ float scr[16 * 193];

  const int tid  = threadIdx.x;
  const int blk  = blockIdx.x;
  const int lane = tid & 63;
  const int ng   = tid >> 6;
  const int r16  = lane & 15;
  const int g    = lane >> 4;
  const int m0   = blk * 16;

  f32x4 acc[3];
#pragma unroll
  for (int s = 0; s < 3; ++s) acc[s] = (f32x4){0.f, 0.f, 0.f, 0.f};

#pragma unroll 2
  for (int step = 0; step < 16; ++step) {
    const int k0 = step * 32;
    const float* xp = x + (size_t)(m0 + r16) * 512 + k0 + g * 8;
    f32x4 xa = *(const f32x4*)xp;
    f32x4 xb = *(const f32x4*)(xp + 4);
    f16x8 a;
#pragma unroll
    for (int j = 0; j < 4; ++j) { a[j] = (f16)xa[j]; a[4 + j] = (f16)xb[j]; }
#pragma unroll
    for (int s = 0; s < 3; ++s) {
      f16x8 b = *(const f16x8*)(w16 + (size_t)(ng * 48 + s * 16 + r16) * 512 + k0 + g * 8);
      acc[s] = __builtin_amdgcn_mfma_f32_16x16x32_f16(a, b, acc[s], 0, 0, 0);
    }
  }

  // dump to LDS scratch: row = g*4+rr, col = ng*48 + s*16 + r16
#pragma unroll
  for (int s = 0; s < 3; ++s)
#pragma unroll
    for (int rr = 0; rr < 4; ++rr)
      scr[(g * 4 + rr) * 193 + ng * 48 + s * 16 + r16] = acc[s][rr];
  __syncthreads();

  u16* Qs = ws + (QS_B >> 1);
  u16* Ks = ws + (KS_B >> 1);
  u16* Vt = ws + (VT_B >> 1);
  // Q and K rows (fp16, row-major): 4 elems per thread each
  {
    int row = tid >> 4, c0 = (tid & 15) * 4;
    __attribute__((aligned(8))) u16 bq[4], bk[4];
#pragma unroll
    for (int j = 0; j < 4; ++j) {
      bq[j] = h16(scr[row * 193 + c0 + j]);
      bk[j] = h16(scr[row * 193 + 64 + c0 + j]);
    }
    *(uint2*)(Qs + (size_t)(m0 + row) * 64 + c0) = *(uint2*)bq;
    *(uint2*)(Ks + (size_t)(m0 + row) * 64 + c0) = *(uint2*)bk;
  }
  // V^T, kv-tiled layout [bb][tile][d][kv32]; block = 16 seq rows = half a tile
  {
    int d = tid >> 2, sg = (tid & 3) * 4;
    int bb = blk >> 8, seq0 = (blk & 255) * 16;
    int tile = seq0 >> 5, s_off = seq0 & 31;
    __attribute__((aligned(8))) u16 bv[4];
#pragma unroll
    for (int j = 0; j < 4; ++j) bv[j] = h16(scr[(sg + j) * 193 + 128 + d]);
    *(uint2*)(Vt + (((size_t)(bb * 128 + tile)) * 64 + d) * 32 + s_off + sg) = *(uint2*)bv;
  }
}

// ---------------- flash attention: 256 blocks x 1024 thr (16 waves = 4/SIMD) ----------
// wave (qh, sl): q rows qt*64+qh*32+l31, kv slice sl*512 (16 iters of 32).
// Main loop: ZERO cross-lane / LDS ops. PV via mfma_32x32x8 (sac regs are direct
// B-fragments). Lane-local defer-max softmax. K self-prefetched across iters.
__global__ __launch_bounds__(1024, 4) void attn_kernel(const u16* __restrict__ ws,
                                                       float* __restrict__ out) {
  __shared__ float oaccs[64][68];
  __shared__ float mls[16][32][2];
  __shared__ float lsum[64];

  const int tid  = threadIdx.x;
  const int w    = tid >> 6;
  const int lane = tid & 63;
  const int l31  = lane & 31;
  const int h    = lane >> 5;
  const int qh   = w & 1;
  const int sl   = w >> 1;
  const int b    = blockIdx.x;
  const int qt   = (b & 7) * 32 + (b >> 3);  // XCD-bijective swizzle
  const int bb   = qt >> 6;

  const u16* Qg = ws + (QS_B >> 1);
  const u16* Kg = ws + (KS_B >> 1) + (size_t)bb * SEQ * 64;
  const u16* Vg = ws + (VT_B >> 1) + (size_t)bb * 128 * 64 * 32;

  // Q fragments (B-operand): lane holds Q[qt*64+qh*32+l31][ch*16 + h*8 + j]
  f16x8 qf[4];
#pragma unroll
  for (int ch = 0; ch < 4; ++ch)
    qf[ch] = *(const f16x8*)(Qg + (size_t)(qt * 64 + qh * 32 + l31) * 64 + ch * 16 + h * 8);

  f32x16 oacc[2];  // O^T [dblk]
#pragma unroll
  for (int db = 0; db < 2; ++db)
#pragma unroll
    for (int r = 0; r < 16; ++r) oacc[db][r] = 0.f;
  float mrun = -INFINITY, lrun = 0.f;
  const float RTHR = 11.0f;  // defer-max (exp2 domain): P <= 2^11, fp16-safe

  // K tile for it=0 (A-operand): lane holds K[kv0+l31][ch*16 + h*8 + j]
  f16x8 ka[4];
#pragma unroll
  for (int ch = 0; ch < 4; ++ch)
    ka[ch] = *(const f16x8*)(Kg + (size_t)(sl * 512 + l31) * 64 + ch * 16 + h * 8);

#pragma unroll 1
  for (int it = 0; it < 16; ++it) {
    const int tile = sl * 16 + it;
    // V^T fragments for PV (A of 32x32x8): lane holds V^T[db*32+l31][c*8 + h*4 + j]
    f16x4 va[2][4];
#pragma unroll
    for (int db = 0; db < 2; ++db)
#pragma unroll
      for (int c = 0; c < 4; ++c)
        va[db][c] = *(const f16x4*)(Vg + (((size_t)tile * 64) + db * 32 + l31) * 32 +
                                    c * 8 + h * 4);

    // S^T = K * Q^T
    f32x16 sac;
#pragma unroll
    for (int r = 0; r < 16; ++r) sac[r] = 0.f;
#pragma unroll
    for (int ch = 0; ch < 4; ++ch)
      sac = __builtin_amdgcn_mfma_f32_32x32x16_f16(ka[ch], qf[ch], sac, 0, 0, 0);

    // self-prefetch next K tile (consumed next iter; hidden under softmax+PV)
    if (it < 15) {
      const int kvn = sl * 512 + (it + 1) * 32;
#pragma unroll
      for (int ch = 0; ch < 4; ++ch)
        ka[ch] = *(const f16x8*)(Kg + (size_t)(kvn + l31) * 64 + ch * 16 + h * 8);
    }

    // lane-local defer-max softmax (no cross-lane ops on the common path)
    float mt = sac[0];
#pragma unroll
    for (int r = 1; r < 16; ++r) mt = fmaxf(mt, sac[r]);
    if (__any(mt > mrun + RTHR)) {
      float mtw  = fmaxf(mt, __shfl_xor(mt, 32));  // rare: exact pair max
      float nm   = fmaxf(mrun, mtw);
      float corr = exp2f(mrun - nm);
      lrun *= corr;
      mrun = nm;
#pragma unroll
      for (int db = 0; db < 2; ++db)
#pragma unroll
        for (int r = 0; r < 16; ++r) oacc[db][r] *= corr;
    }
#pragma unroll
    for (int r = 0; r < 16; ++r) {
      float pv = exp2f(sac[r] - mrun);
      sac[r] = pv;
      lrun += pv;
    }

    // P -> B-fragments of 32x32x8 directly (regs 4c..4c+3 = kv 8c+4h+j): no shuffle
    f16x4 pb[4];
#pragma unroll
    for (int c = 0; c < 4; ++c) {
      u32x2 pk;
      pk[0] = pkrtz(sac[4 * c + 0], sac[4 * c + 1]);
      pk[1] = pkrtz(sac[4 * c + 2], sac[4 * c + 3]);
      pb[c] = __builtin_bit_cast(f16x4, pk);
    }

    // O^T += V^T * P^T  (8 x mfma_32x32x8)
#pragma unroll
    for (int db = 0; db < 2; ++db)
#pragma unroll
      for (int c = 0; c < 4; ++c)
        oacc[db] = __builtin_amdgcn_mfma_f32_32x32x8f16(va[db][c], pb[c], oacc[db], 0, 0, 0);
  }

  // combine per-lane l across the kv-half pair (one shuffle total)
  lrun += __shfl_xor(lrun, 32);

  // ---- in-LDS merge across 16 waves ----
  if (h == 0) {
    mls[w][l31][0] = mrun;
    mls[w][l31][1] = lrun;
  }
  for (int idx = tid; idx < 64 * 68; idx += 1024) ((float*)oaccs)[idx] = 0.f;
  __syncthreads();

  float mg = -INFINITY;
#pragma unroll
  for (int ww = 0; ww < 8; ++ww) mg = fmaxf(mg, mls[ww * 2 + qh][l31][0]);
  float lg = 0.f;
#pragma unroll
  for (int ww = 0; ww < 8; ++ww)
    lg += mls[ww * 2 + qh][l31][1] * exp2f(mls[ww * 2 + qh][l31][0] - mg);
  float wgt = exp2f(mrun - mg);
  if (w < 2 && h == 0) lsum[qh * 32 + l31] = lg;

#pragma unroll
  for (int db = 0; db < 2; ++db)
#pragma unroll
    for (int r = 0; r < 16; ++r) {
      int d = db * 32 + (r & 3) + 8 * (r >> 2) + 4 * h;
      atomicAdd(&oaccs[qh * 32 + l31][d], oacc[db][r] * wgt);
    }
  __syncthreads();

  {
    int q = tid >> 4, c = (tid & 15) * 4;
    float inv = 1.f / lsum[q];
    f32x4 v = *(const f32x4*)&oaccs[q][c];
    v *= inv;
    *(f32x4*)(out + (size_t)(qt * 64 + q) * 64 + c) = v;
  }
}

extern "C" void kernel_launch(void* const* d_in, const int* in_sizes, int n_in,
                              void* d_out, int out_size, void* d_ws, size_t ws_size,
                              hipStream_t stream) {
  const float* x  = (const float*)d_in[0];
  const float* Wq = (const float*)d_in[1];
  const float* Wk = (const float*)d_in[2];
  const float* Wv = (const float*)d_in[3];
  u16* ws = (u16*)d_ws;
  (void)in_sizes; (void)n_in; (void)out_size; (void)ws_size;

  wconv_kernel<<<96, 256, 0, stream>>>(Wq, Wk, Wv, ws + (W16_B >> 1));
  proj_kernel<<<1024, 256, 0, stream>>>(x, ws + (W16_B >> 1), ws);
  attn_kernel<<<256, 1024, 0, stream>>>(ws, (float*)d_out);
}

// Round 8
// 95.342 us; speedup vs baseline: 1.5747x; 1.5747x over previous
//
#include <hip/hip_runtime.h>
#include <hip/hip_bf16.h>

#define SEQ 4096
#define MTOT 16384

typedef float f32x4  __attribute__((ext_vector_type(4)));
typedef float f32x16 __attribute__((ext_vector_type(16)));
typedef _Float16 f16;
typedef _Float16 f16x4 __attribute__((ext_vector_type(4)));
typedef _Float16 f16x8 __attribute__((ext_vector_type(8)));
typedef unsigned int   u32;
typedef unsigned int   u32x2 __attribute__((ext_vector_type(2)));
typedef unsigned short u16;

// ws byte offsets — ALL tensors in MFMA fragment-linear layout.
// Q_lin [qhalf(512)][ch(4)][lane(64)][8]   : lane(l31,h) = Q[qhalf*32+l31][ch*16+h*8+j]
// K_lin [tile(512)][ch(4)][lane(64)][8]    : lane(l31,h) = K[tile*32+l31][ch*16+h*8+j]
// V_lin [tile(512)][db(2)][p(2)][lane(64)][8]: lane(l31,h), q<4: V[tile*32+16p+4h+q][db*32+l31]
//                                              q>=4:        V[tile*32+16p+8+4h+(q-4)][db*32+l31]
// W_lin [s(12)][step(16)][lane(64)][8]     : lane(r16,g) = W[s*16+r16][step*32+g*8+j] (Wq scaled)
static constexpr size_t QL_B = 0;
static constexpr size_t KL_B = 2u << 20;
static constexpr size_t VL_B = 4u << 20;
static constexpr size_t WL_B = 6u << 20;

__device__ __forceinline__ u16 h16(float v) { return __builtin_bit_cast(u16, (f16)v); }
__device__ __forceinline__ u32 pkrtz(float a, float b) {
  return __builtin_bit_cast(u32, __builtin_amdgcn_cvt_pkrtz(a, b));
}

// ---------------- W fp32 -> fragment-linear fp16 (Wq folded with 0.125*log2e) ----------
__global__ __launch_bounds__(256) void wconv_kernel(const float* __restrict__ Wq,
                                                    const float* __restrict__ Wk,
                                                    const float* __restrict__ Wv,
                                                    u16* __restrict__ wlin) {
  const float QSC = 0.18033688011112042f;  // 0.125 * log2(e)
  int e = blockIdx.x * 256 + threadIdx.x;  // [0, 24576) f32x4 chunks
  int flat = e * 4;
  int colg = flat >> 9;             // global col 0..191
  int k0   = flat & 511;
  int mat  = colg >> 6;
  const float* W = (mat == 0) ? Wq : (mat == 1 ? Wk : Wv);
  f32x4 v = *(const f32x4*)(W + (size_t)(colg & 63) * 512 + k0);
  if (mat == 0) v *= QSC;
  int s = colg >> 4, r16 = colg & 15;
  int step = k0 >> 5, g = (k0 & 31) >> 3, jb = k0 & 7;
  __attribute__((aligned(8))) u16 b[4];
#pragma unroll
  for (int j = 0; j < 4; ++j) b[j] = h16(v[j]);
  *(uint2*)(wlin + ((size_t)(s * 16 + step) * 64 + g * 16 + r16) * 8 + jb) = *(uint2*)b;
}

// ---------------- QKV projection ----------------
// 1024 blocks x 256 thr (4 waves). Block: 16 x-rows. x staged to LDS in fragment-linear
// form (coalesced global in, lane-linear ds_read_b128 out); W from fragment-linear L2.
__global__ __launch_bounds__(256, 4) void proj_kernel(const float* __restrict__ x,
                                                      const u16* __restrict__ wlin,
                                                      u16* __restrict__ ws) {
  __shared__ __attribute__((aligned(16))) u16 xl[8192];  // 16KB; scr overlay 12.3KB
  float* scr = (float*)xl;

  const int tid  = threadIdx.x;
  const int blk  = blockIdx.x;
  const int lane = tid & 63;
  const int ng   = tid >> 6;
  const int r16  = lane & 15;
  const int g    = lane >> 4;
  const int m0   = blk * 16;

  // stage x[16][512] -> fragment-linear LDS (A-operand order)
#pragma unroll
  for (int i = 0; i < 8; ++i) {
    int f = tid * 4 + i * 1024;
    int row = f >> 9, k0 = f & 511;
    f32x4 v = *(const f32x4*)(x + (size_t)m0 * 512 + f);
    __attribute__((aligned(8))) u16 b[4];
#pragma unroll
    for (int j = 0; j < 4; ++j) b[j] = h16(v[j]);
    int ln = ((k0 & 31) >> 3) * 16 + row;
    *(uint2*)(xl + ((size_t)(k0 >> 5) * 64 + ln) * 8 + (k0 & 7)) = *(uint2*)b;
  }
  __syncthreads();

  f32x4 acc[3];
#pragma unroll
  for (int s = 0; s < 3; ++s) acc[s] = (f32x4){0.f, 0.f, 0.f, 0.f};

#pragma unroll 2
  for (int step = 0; step < 16; ++step) {
    f16x8 a = *(const f16x8*)(xl + ((size_t)step * 64 + lane) * 8);
#pragma unroll
    for (int s = 0; s < 3; ++s) {
      int sg = ng * 3 + s;
      f16x8 b = *(const f16x8*)(wlin + ((size_t)(sg * 16 + step) * 64 + lane) * 8);
      acc[s] = __builtin_amdgcn_mfma_f32_16x16x32_f16(a, b, acc[s], 0, 0, 0);
    }
  }
  __syncthreads();  // done with xl; reuse as scr

  // dump accumulators: scr[row16][col192] (pad 193)
#pragma unroll
  for (int s = 0; s < 3; ++s)
#pragma unroll
    for (int rr = 0; rr < 4; ++rr)
      scr[(g * 4 + rr) * 193 + ng * 48 + s * 16 + r16] = acc[s][rr];
  __syncthreads();

  u16* Ql = ws + (QL_B >> 1);
  u16* Kl = ws + (KL_B >> 1);
  u16* Vl = ws + (VL_B >> 1);
  const int batch = m0 >> 12;
  const int tile  = (m0 >> 5) & 127;
  const int half  = (m0 >> 4) & 1;

  // K (threads 0..127) and Q (threads 128..255): 16B fragment chunks
  {
    int t2 = tid & 127;
    int r  = t2 & 15, hh = (t2 >> 4) & 1, ch = t2 >> 5;
    int l31 = half * 16 + r;
    __attribute__((aligned(16))) u16 b[8];
    if (tid < 128) {
#pragma unroll
      for (int j = 0; j < 8; ++j) b[j] = h16(scr[r * 193 + 64 + ch * 16 + hh * 8 + j]);
      *(uint4*)(Kl + ((size_t)((batch * 128 + tile) * 4 + ch) * 64 + hh * 32 + l31) * 8) =
          *(uint4*)b;
    } else {
#pragma unroll
      for (int j = 0; j < 8; ++j) b[j] = h16(scr[r * 193 + ch * 16 + hh * 8 + j]);
      int qhalf = (m0 >> 5);  // = global_row>>5
      *(uint4*)(Ql + ((size_t)(qhalf * 4 + ch) * 64 + hh * 32 + l31) * 8) = *(uint4*)b;
    }
  }
  // V: all 256 threads, 8B chunks
  {
    int z = tid & 1, l31 = (tid >> 1) & 31, hh = (tid >> 6) & 1, db = tid >> 7;
    int d = db * 32 + l31;
    __attribute__((aligned(8))) u16 b[4];
#pragma unroll
    for (int j = 0; j < 4; ++j) b[j] = h16(scr[(8 * z + 4 * hh + j) * 193 + 128 + d]);
    *(uint2*)(Vl + ((size_t)(((batch * 128 + tile) * 2 + db) * 2 + half) * 64 + hh * 32 + l31) *
                       8 + z * 4) = *(uint2*)b;
  }
}

// ---------------- flash attention: 256 blocks x 1024 thr (16 waves = 4/SIMD) ----------
// wave (qh, sl): q rows qt*64+qh*32+l31, kv slice sl*512 (16 iters of 32). All loads
// fragment-linear coalesced b128. Zero cross-lane ops in main loop (32x32x8 PV).
__global__ __launch_bounds__(1024, 4) void attn_kernel(const u16* __restrict__ ws,
                                                       float* __restrict__ out) {
  __shared__ float oaccs[64][68];
  __shared__ float mls[16][32][2];
  __shared__ float lsum[64];

  const int tid  = threadIdx.x;
  const int w    = tid >> 6;
  const int lane = tid & 63;
  const int l31  = lane & 31;
  const int h    = lane >> 5;
  const int qh   = w & 1;
  const int sl   = w >> 1;
  const int b    = blockIdx.x;
  const int qt   = (b & 7) * 32 + (b >> 3);  // XCD-bijective swizzle
  const int bb   = qt >> 6;

  const u16* Ql = ws + (QL_B >> 1);
  const u16* Kl = ws + (KL_B >> 1);
  const u16* Vl = ws + (VL_B >> 1);

  // Q fragments (B-operand of QK^T)
  f16x8 qf[4];
#pragma unroll
  for (int ch = 0; ch < 4; ++ch)
    qf[ch] = *(const f16x8*)(Ql + ((size_t)((qt * 2 + qh) * 4 + ch) * 64 + lane) * 8);

  f32x16 oacc[2];
#pragma unroll
  for (int db = 0; db < 2; ++db)
#pragma unroll
    for (int r = 0; r < 16; ++r) oacc[db][r] = 0.f;
  float mrun = -INFINITY, lrun = 0.f;
  const float RTHR = 11.0f;  // defer-max (exp2 domain): P <= 2^11, fp16-safe

  // K tile it=0
  f16x8 ka[4];
#pragma unroll
  for (int ch = 0; ch < 4; ++ch)
    ka[ch] = *(const f16x8*)(Kl + ((size_t)((bb * 128 + sl * 16) * 4 + ch) * 64 + lane) * 8);

#pragma unroll 1
  for (int it = 0; it < 16; ++it) {
    const size_t kt = (size_t)(bb * 128 + sl * 16 + it);
    // V fragments: 4 coalesced b128; each splits into two f16x4 A-operands
    f16x8 vp[2][2];
#pragma unroll
    for (int db = 0; db < 2; ++db)
#pragma unroll
      for (int p = 0; p < 2; ++p)
        vp[db][p] = *(const f16x8*)(Vl + (((kt * 2 + db) * 2 + p) * 64 + lane) * 8);

    // S^T = K * Q^T
    f32x16 sac;
#pragma unroll
    for (int r = 0; r < 16; ++r) sac[r] = 0.f;
#pragma unroll
    for (int ch = 0; ch < 4; ++ch)
      sac = __builtin_amdgcn_mfma_f32_32x32x16_f16(ka[ch], qf[ch], sac, 0, 0, 0);

    // self-prefetch next K tile
    if (it < 15) {
#pragma unroll
      for (int ch = 0; ch < 4; ++ch)
        ka[ch] = *(const f16x8*)(Kl + (((kt + 1) * 4 + ch) * 64 + lane) * 8);
    }

    // lane-local defer-max softmax
    float mt = sac[0];
#pragma unroll
    for (int r = 1; r < 16; ++r) mt = fmaxf(mt, sac[r]);
    if (__any(mt > mrun + RTHR)) {
      float mtw  = fmaxf(mt, __shfl_xor(mt, 32));
      float nm   = fmaxf(mrun, mtw);
      float corr = exp2f(mrun - nm);
      lrun *= corr;
      mrun = nm;
#pragma unroll
      for (int db = 0; db < 2; ++db)
#pragma unroll
        for (int r = 0; r < 16; ++r) oacc[db][r] *= corr;
    }
#pragma unroll
    for (int r = 0; r < 16; ++r) {
      float pv = exp2f(sac[r] - mrun);
      sac[r] = pv;
      lrun += pv;
    }

    // P -> B-fragments of 32x32x8 (regs 4c..4c+3 map directly): no shuffle
    f16x4 pb[4];
#pragma unroll
    for (int c = 0; c < 4; ++c) {
      u32x2 pk;
      pk[0] = pkrtz(sac[4 * c + 0], sac[4 * c + 1]);
      pk[1] = pkrtz(sac[4 * c + 2], sac[4 * c + 3]);
      pb[c] = __builtin_bit_cast(f16x4, pk);
    }

    // O^T += V^T * P^T
#pragma unroll
    for (int db = 0; db < 2; ++db)
#pragma unroll
      for (int p = 0; p < 2; ++p) {
        f16x4 vlo = __builtin_shufflevector(vp[db][p], vp[db][p], 0, 1, 2, 3);
        f16x4 vhi = __builtin_shufflevector(vp[db][p], vp[db][p], 4, 5, 6, 7);
        oacc[db] = __builtin_amdgcn_mfma_f32_32x32x8f16(vlo, pb[2 * p], oacc[db], 0, 0, 0);
        oacc[db] = __builtin_amdgcn_mfma_f32_32x32x8f16(vhi, pb[2 * p + 1], oacc[db], 0, 0, 0);
      }
  }

  lrun += __shfl_xor(lrun, 32);

  // ---- in-LDS merge across 16 waves ----
  if (h == 0) {
    mls[w][l31][0] = mrun;
    mls[w][l31][1] = lrun;
  }
  for (int idx = tid; idx < 64 * 68; idx += 1024) ((float*)oaccs)[idx] = 0.f;
  __syncthreads();

  float mg = -INFINITY;
#pragma unroll
  for (int ww = 0; ww < 8; ++ww) mg = fmaxf(mg, mls[ww * 2 + qh][l31][0]);
  float lg = 0.f;
#pragma unroll
  for (int ww = 0; ww < 8; ++ww)
    lg += mls[ww * 2 + qh][l31][1] * exp2f(mls[ww * 2 + qh][l31][0] - mg);
  float wgt = exp2f(mrun - mg);
  if (w < 2 && h == 0) lsum[qh * 32 + l31] = lg;

#pragma unroll
  for (int db = 0; db < 2; ++db)
#pragma unroll
    for (int r = 0; r < 16; ++r) {
      int d = db * 32 + (r & 3) + 8 * (r >> 2) + 4 * h;
      atomicAdd(&oaccs[qh * 32 + l31][d], oacc[db][r] * wgt);
    }
  __syncthreads();

  {
    int q = tid >> 4, c = (tid & 15) * 4;
    float inv = 1.f / lsum[q];
    f32x4 v = *(const f32x4*)&oaccs[q][c];
    v *= inv;
    *(f32x4*)(out + (size_t)(qt * 64 + q) * 64 + c) = v;
  }
}

extern "C" void kernel_launch(void* const* d_in, const int* in_sizes, int n_in,
                              void* d_out, int out_size, void* d_ws, size_t ws_size,
                              hipStream_t stream) {
  const float* x  = (const float*)d_in[0];
  const float* Wq = (const float*)d_in[1];
  const float* Wk = (const float*)d_in[2];
  const float* Wv = (const float*)d_in[3];
  u16* ws = (u16*)d_ws;
  (void)in_sizes; (void)n_in; (void)out_size; (void)ws_size;

  wconv_kernel<<<96, 256, 0, stream>>>(Wq, Wk, Wv, ws + (WL_B >> 1));
  proj_kernel<<<1024, 256, 0, stream>>>(x, ws + (WL_B >> 1), ws);
  attn_kernel<<<256, 1024, 0, stream>>>(ws, (float*)d_out);
}

// Round 9
// 65.813 us; speedup vs baseline: 2.2812x; 1.4487x over previous
//
#include <hip/hip_runtime.h>
#include <hip/hip_bf16.h>

#define SEQ 4096
#define MTOT 16384

typedef float f32x4  __attribute__((ext_vector_type(4)));
typedef float f32x16 __attribute__((ext_vector_type(16)));
typedef _Float16 f16;
typedef _Float16 f16x4 __attribute__((ext_vector_type(4)));
typedef _Float16 f16x8 __attribute__((ext_vector_type(8)));
typedef unsigned int   u32;
typedef unsigned int   u32x2 __attribute__((ext_vector_type(2)));
typedef unsigned short u16;

// ws byte offsets — Q/K/V/W in MFMA fragment-linear layout (see round-8 comments).
static constexpr size_t QL_B   = 0;           // [qhalf(512)][ch(4)][lane(64)][8]   2MB
static constexpr size_t KL_B   = 2u << 20;    // [tile(512)][ch(4)][lane(64)][8]    2MB
static constexpr size_t VL_B   = 4u << 20;    // [tile(512)][db2][p2][lane(64)][8]  2MB
static constexpr size_t WL_B   = 6u << 20;    // fp16 W fragment-linear           192KB
static constexpr size_t PART_B = 8u << 20;    // fp32 partial O [8][16384][64]   33.5MB
static constexpr size_t ML_B   = 42u << 20;   // fp32 m[8][16384], l[8][16384]      1MB

__device__ __forceinline__ u16 h16(float v) { return __builtin_bit_cast(u16, (f16)v); }
__device__ __forceinline__ u32 pkrtz(float a, float b) {
  return __builtin_bit_cast(u32, __builtin_amdgcn_cvt_pkrtz(a, b));
}
__device__ __forceinline__ void gl16(const u16* g, u16* l) {
  __builtin_amdgcn_global_load_lds((const __attribute__((address_space(1))) void*)g,
                                   (__attribute__((address_space(3))) void*)l, 16, 0, 0);
}

// ---------------- W fp32 -> fragment-linear fp16 (Wq folded with 0.125*log2e) ----------
__global__ __launch_bounds__(256) void wconv_kernel(const float* __restrict__ Wq,
                                                    const float* __restrict__ Wk,
                                                    const float* __restrict__ Wv,
                                                    u16* __restrict__ wlin) {
  const float QSC = 0.18033688011112042f;  // 0.125 * log2(e)
  int e = blockIdx.x * 256 + threadIdx.x;  // [0, 24576) f32x4 chunks
  int flat = e * 4;
  int colg = flat >> 9;
  int k0   = flat & 511;
  int mat  = colg >> 6;
  const float* W = (mat == 0) ? Wq : (mat == 1 ? Wk : Wv);
  f32x4 v = *(const f32x4*)(W + (size_t)(colg & 63) * 512 + k0);
  if (mat == 0) v *= QSC;
  int s = colg >> 4, r16 = colg & 15;
  int step = k0 >> 5, g = (k0 & 31) >> 3, jb = k0 & 7;
  __attribute__((aligned(8))) u16 b[4];
#pragma unroll
  for (int j = 0; j < 4; ++j) b[j] = h16(v[j]);
  *(uint2*)(wlin + ((size_t)(s * 16 + step) * 64 + g * 16 + r16) * 8 + jb) = *(uint2*)b;
}

// ---------------- QKV projection (unchanged from round 8) ----------------
__global__ __launch_bounds__(256, 4) void proj_kernel(const float* __restrict__ x,
                                                      const u16* __restrict__ wlin,
                                                      u16* __restrict__ ws) {
  __shared__ __attribute__((aligned(16))) u16 xl[8192];
  float* scr = (float*)xl;

  const int tid  = threadIdx.x;
  const int blk  = blockIdx.x;
  const int lane = tid & 63;
  const int ng   = tid >> 6;
  const int r16  = lane & 15;
  const int g    = lane >> 4;
  const int m0   = blk * 16;

#pragma unroll
  for (int i = 0; i < 8; ++i) {
    int f = tid * 4 + i * 1024;
    int row = f >> 9, k0 = f & 511;
    f32x4 v = *(const f32x4*)(x + (size_t)m0 * 512 + f);
    __attribute__((aligned(8))) u16 b[4];
#pragma unroll
    for (int j = 0; j < 4; ++j) b[j] = h16(v[j]);
    int ln = ((k0 & 31) >> 3) * 16 + row;
    *(uint2*)(xl + ((size_t)(k0 >> 5) * 64 + ln) * 8 + (k0 & 7)) = *(uint2*)b;
  }
  __syncthreads();

  f32x4 acc[3];
#pragma unroll
  for (int s = 0; s < 3; ++s) acc[s] = (f32x4){0.f, 0.f, 0.f, 0.f};

#pragma unroll 2
  for (int step = 0; step < 16; ++step) {
    f16x8 a = *(const f16x8*)(xl + ((size_t)step * 64 + lane) * 8);
#pragma unroll
    for (int s = 0; s < 3; ++s) {
      int sg = ng * 3 + s;
      f16x8 b = *(const f16x8*)(wlin + ((size_t)(sg * 16 + step) * 64 + lane) * 8);
      acc[s] = __builtin_amdgcn_mfma_f32_16x16x32_f16(a, b, acc[s], 0, 0, 0);
    }
  }
  __syncthreads();

#pragma unroll
  for (int s = 0; s < 3; ++s)
#pragma unroll
    for (int rr = 0; rr < 4; ++rr)
      scr[(g * 4 + rr) * 193 + ng * 48 + s * 16 + r16] = acc[s][rr];
  __syncthreads();

  u16* Ql = ws + (QL_B >> 1);
  u16* Kl = ws + (KL_B >> 1);
  u16* Vl = ws + (VL_B >> 1);
  const int batch = m0 >> 12;
  const int tile  = (m0 >> 5) & 127;
  const int half  = (m0 >> 4) & 1;

  {
    int t2 = tid & 127;
    int r  = t2 & 15, hh = (t2 >> 4) & 1, ch = t2 >> 5;
    int l31 = half * 16 + r;
    __attribute__((aligned(16))) u16 b[8];
    if (tid < 128) {
#pragma unroll
      for (int j = 0; j < 8; ++j) b[j] = h16(scr[r * 193 + 64 + ch * 16 + hh * 8 + j]);
      *(uint4*)(Kl + ((size_t)((batch * 128 + tile) * 4 + ch) * 64 + hh * 32 + l31) * 8) =
          *(uint4*)b;
    } else {
#pragma unroll
      for (int j = 0; j < 8; ++j) b[j] = h16(scr[r * 193 + ch * 16 + hh * 8 + j]);
      int qhalf = (m0 >> 5);
      *(uint4*)(Ql + ((size_t)(qhalf * 4 + ch) * 64 + hh * 32 + l31) * 8) = *(uint4*)b;
    }
  }
  {
    int z = tid & 1, l31 = (tid >> 1) & 31, hh = (tid >> 6) & 1, db = tid >> 7;
    int d = db * 32 + l31;
    __attribute__((aligned(8))) u16 b[4];
#pragma unroll
    for (int j = 0; j < 4; ++j) b[j] = h16(scr[(8 * z + 4 * hh + j) * 193 + 128 + d]);
    *(uint2*)(Vl + ((size_t)(((batch * 128 + tile) * 2 + db) * 2 + half) * 64 + hh * 32 + l31) *
                       8 + z * 4) = *(uint2*)b;
  }
}

// ---------------- flash attention: LDS-shared K/V tiles ----------------
// 256 blocks (32 q-blocks x 8 kv-splits; blockIdx%8 = split -> XCD L2 locality).
// Block: 1024 thr = 16 waves; wave w owns q rows qb*512 + w*32 (exclusive -> no merge).
// Per iter: wave 15 stages next 8KB K+V tile (linear memcpy) via global_load_lds into
// LDS dbuf; all waves ds_read_b128 fragments. 16 iters of 32 kv.
__global__ __launch_bounds__(1024, 4) void attn_kernel(u16* __restrict__ ws) {
  __shared__ __attribute__((aligned(16))) u16 kvbuf[2][2][2048];  // [buf][K|V][4KB]

  const int tid  = threadIdx.x;
  const int w    = tid >> 6;
  const int lane = tid & 63;
  const int l31  = lane & 31;
  const int h    = lane >> 5;
  const int bx   = blockIdx.x;
  const int qb   = bx >> 3;     // 0..31
  const int sp   = bx & 7;      // kv split
  const int bb   = qb >> 3;     // batch
  const int q0   = qb * 512 + w * 32;

  const u16* Ql = ws + (QL_B >> 1);
  const u16* Kl = ws + (KL_B >> 1);
  const u16* Vl = ws + (VL_B >> 1);

  // Q fragments (B-operand of QK^T)
  const int qhalf = qb * 16 + w;
  f16x8 qf[4];
#pragma unroll
  for (int ch = 0; ch < 4; ++ch)
    qf[ch] = *(const f16x8*)(Ql + ((size_t)(qhalf * 4 + ch) * 64 + lane) * 8);

  f32x16 oacc[2];
#pragma unroll
  for (int db = 0; db < 2; ++db)
#pragma unroll
    for (int r = 0; r < 16; ++r) oacc[db][r] = 0.f;
  float mrun = -INFINITY, lrun = 0.f;
  const float RTHR = 11.0f;

  const int kt0 = bb * 128 + sp * 16;  // global 32-kv tile base

  // prologue: stage tile 0 -> buf 0
  if (w == 15) {
    const u16* ks = Kl + (size_t)kt0 * 2048;
    const u16* vs = Vl + (size_t)kt0 * 2048;
#pragma unroll
    for (int c = 0; c < 4; ++c) gl16(ks + c * 512 + lane * 8, &kvbuf[0][0][c * 512]);
#pragma unroll
    for (int c = 0; c < 4; ++c) gl16(vs + c * 512 + lane * 8, &kvbuf[0][1][c * 512]);
  }
  __syncthreads();

#pragma unroll 1
  for (int it = 0; it < 16; ++it) {
    const int cur = it & 1;
    // stage next tile into the other buffer (overlaps with this iter's compute)
    if (w == 15 && it < 15) {
      const u16* ks = Kl + (size_t)(kt0 + it + 1) * 2048;
      const u16* vs = Vl + (size_t)(kt0 + it + 1) * 2048;
#pragma unroll
      for (int c = 0; c < 4; ++c) gl16(ks + c * 512 + lane * 8, &kvbuf[cur ^ 1][0][c * 512]);
#pragma unroll
      for (int c = 0; c < 4; ++c) gl16(vs + c * 512 + lane * 8, &kvbuf[cur ^ 1][1][c * 512]);
    }

    // fragments from LDS (lane-linear b128, conflict-free)
    f16x8 ka[4], vp[2][2];
#pragma unroll
    for (int ch = 0; ch < 4; ++ch)
      ka[ch] = *(const f16x8*)&kvbuf[cur][0][(ch * 64 + lane) * 8];
#pragma unroll
    for (int db = 0; db < 2; ++db)
#pragma unroll
      for (int p = 0; p < 2; ++p)
        vp[db][p] = *(const f16x8*)&kvbuf[cur][1][((db * 2 + p) * 64 + lane) * 8];

    // S^T = K * Q^T
    f32x16 sac;
#pragma unroll
    for (int r = 0; r < 16; ++r) sac[r] = 0.f;
#pragma unroll
    for (int ch = 0; ch < 4; ++ch)
      sac = __builtin_amdgcn_mfma_f32_32x32x16_f16(ka[ch], qf[ch], sac, 0, 0, 0);

    // lane-local defer-max softmax
    float mt = sac[0];
#pragma unroll
    for (int r = 1; r < 16; ++r) mt = fmaxf(mt, sac[r]);
    if (__any(mt > mrun + RTHR)) {
      float mtw  = fmaxf(mt, __shfl_xor(mt, 32));
      float nm   = fmaxf(mrun, mtw);
      float corr = exp2f(mrun - nm);
      lrun *= corr;
      mrun = nm;
#pragma unroll
      for (int db = 0; db < 2; ++db)
#pragma unroll
        for (int r = 0; r < 16; ++r) oacc[db][r] *= corr;
    }
#pragma unroll
    for (int r = 0; r < 16; ++r) {
      float pv = exp2f(sac[r] - mrun);
      sac[r] = pv;
      lrun += pv;
    }

    // P -> B-fragments of 32x32x8 directly (no cross-lane ops)
    f16x4 pb[4];
#pragma unroll
    for (int c = 0; c < 4; ++c) {
      u32x2 pk;
      pk[0] = pkrtz(sac[4 * c + 0], sac[4 * c + 1]);
      pk[1] = pkrtz(sac[4 * c + 2], sac[4 * c + 3]);
      pb[c] = __builtin_bit_cast(f16x4, pk);
    }

    // O^T += V^T * P^T
#pragma unroll
    for (int db = 0; db < 2; ++db)
#pragma unroll
      for (int p = 0; p < 2; ++p) {
        f16x4 vlo = __builtin_shufflevector(vp[db][p], vp[db][p], 0, 1, 2, 3);
        f16x4 vhi = __builtin_shufflevector(vp[db][p], vp[db][p], 4, 5, 6, 7);
        oacc[db] = __builtin_amdgcn_mfma_f32_32x32x8f16(vlo, pb[2 * p], oacc[db], 0, 0, 0);
        oacc[db] = __builtin_amdgcn_mfma_f32_32x32x8f16(vhi, pb[2 * p + 1], oacc[db], 0, 0, 0);
      }

    __syncthreads();  // all waves done with buf[cur]; wave15's stage drained
  }

  lrun += __shfl_xor(lrun, 32);

  // epilogue: unnormalized partial O + (m,l); q-rows exclusive per wave
  float* Op = (float*)((char*)ws + PART_B) + (size_t)sp * MTOT * 64;
#pragma unroll
  for (int db = 0; db < 2; ++db)
#pragma unroll
    for (int r = 0; r < 16; ++r) {
      int d = db * 32 + (r & 3) + 8 * (r >> 2) + 4 * h;
      Op[(size_t)(q0 + l31) * 64 + d] = oacc[db][r];
    }
  if (h == 0) {
    float* Mm = (float*)((char*)ws + ML_B);
    float* Ll = Mm + 8 * MTOT;
    Mm[(size_t)sp * MTOT + q0 + l31] = mrun;
    Ll[(size_t)sp * MTOT + q0 + l31] = lrun;
  }
}

// ---------------- merge the 8 kv-splits ----------------
__global__ __launch_bounds__(256) void merge_kernel(const u16* __restrict__ ws,
                                                    float* __restrict__ out) {
  int gid = blockIdx.x * 256 + threadIdx.x;  // 65536 threads
  int row = gid >> 2, dg = gid & 3;
  const float* Mm = (const float*)((const char*)ws + ML_B);
  const float* Ll = Mm + 8 * MTOT;
  float mv[8];
  float mg = -INFINITY;
#pragma unroll
  for (int i = 0; i < 8; ++i) {
    mv[i] = Mm[(size_t)i * MTOT + row];
    mg = fmaxf(mg, mv[i]);
  }
  float den = 0.f, wv[8];
#pragma unroll
  for (int i = 0; i < 8; ++i) {
    wv[i] = exp2f(mv[i] - mg);
    den += wv[i] * Ll[(size_t)i * MTOT + row];
  }
  f32x4 acc[4];
#pragma unroll
  for (int m = 0; m < 4; ++m) acc[m] = (f32x4){0.f, 0.f, 0.f, 0.f};
  const float* Op = (const float*)((const char*)ws + PART_B);
#pragma unroll
  for (int i = 0; i < 8; ++i)
#pragma unroll
    for (int m = 0; m < 4; ++m) {
      f32x4 t = *(const f32x4*)(Op + ((size_t)i * MTOT + row) * 64 + dg * 16 + m * 4);
      acc[m] += wv[i] * t;
    }
  float inv = 1.f / den;
#pragma unroll
  for (int m = 0; m < 4; ++m) {
    f32x4 r = acc[m] * inv;
    *(f32x4*)(out + (size_t)row * 64 + dg * 16 + m * 4) = r;
  }
}

extern "C" void kernel_launch(void* const* d_in, const int* in_sizes, int n_in,
                              void* d_out, int out_size, void* d_ws, size_t ws_size,
                              hipStream_t stream) {
  const float* x  = (const float*)d_in[0];
  const float* Wq = (const float*)d_in[1];
  const float* Wk = (const float*)d_in[2];
  const float* Wv = (const float*)d_in[3];
  u16* ws = (u16*)d_ws;
  (void)in_sizes; (void)n_in; (void)out_size; (void)ws_size;

  wconv_kernel<<<96, 256, 0, stream>>>(Wq, Wk, Wv, ws + (WL_B >> 1));
  proj_kernel<<<1024, 256, 0, stream>>>(x, ws + (WL_B >> 1), ws);
  attn_kernel<<<256, 1024, 0, stream>>>(ws);
  merge_kernel<<<256, 256, 0, stream>>>(ws, (float*)d_out);
}

// Round 10
// 64.694 us; speedup vs baseline: 2.3207x; 1.0173x over previous
//
#include <hip/hip_runtime.h>
#include <hip/hip_bf16.h>

#define SEQ 4096
#define MTOT 16384

typedef float f32x4  __attribute__((ext_vector_type(4)));
typedef float f32x16 __attribute__((ext_vector_type(16)));
typedef _Float16 f16;
typedef _Float16 f16x4 __attribute__((ext_vector_type(4)));
typedef _Float16 f16x8 __attribute__((ext_vector_type(8)));
typedef unsigned int   u32;
typedef unsigned int   u32x2 __attribute__((ext_vector_type(2)));
typedef unsigned short u16;

// ws byte offsets — Q/K/V/W in MFMA fragment-linear layout.
// Q_lin [qhalf(512)][ch(4)][lane(64)][8] : lane(l31,h) = Q[qhalf*32+l31][ch*16+h*8+j]
// K_lin [tile(512)][ch(4)][lane(64)][8]  : lane(l31,h) = K[tile*32+l31][ch*16+h*8+j]
// V_lin [tile(512)][db2][p2][lane(64)][8]
// W_lin [s(12)][step(16)][lane(64)][8]   (Wq pre-scaled by 0.125*log2e)
static constexpr size_t QL_B   = 0;           // 2MB
static constexpr size_t KL_B   = 2u << 20;    // 2MB
static constexpr size_t VL_B   = 4u << 20;    // 2MB
static constexpr size_t WL_B   = 6u << 20;    // 192KB
static constexpr size_t PART_B = 8u << 20;    // fp32 partial O [8][16384][64] 33.5MB
static constexpr size_t ML_B   = 42u << 20;   // fp32 m[8][16384], l[8][16384]

__device__ __forceinline__ u16 h16(float v) { return __builtin_bit_cast(u16, (f16)v); }
__device__ __forceinline__ u32 pkrtz(float a, float b) {
  return __builtin_bit_cast(u32, __builtin_amdgcn_cvt_pkrtz(a, b));
}
__device__ __forceinline__ void gl16(const u16* g, u16* l) {
  __builtin_amdgcn_global_load_lds((const __attribute__((address_space(1))) void*)g,
                                   (__attribute__((address_space(3))) void*)l, 16, 0, 0);
}

// ---------------- W fp32 -> fragment-linear fp16 ----------------
__global__ __launch_bounds__(256) void wconv_kernel(const float* __restrict__ Wq,
                                                    const float* __restrict__ Wk,
                                                    const float* __restrict__ Wv,
                                                    u16* __restrict__ wlin) {
  const float QSC = 0.18033688011112042f;  // 0.125 * log2(e)
  int e = blockIdx.x * 256 + threadIdx.x;
  int flat = e * 4;
  int colg = flat >> 9;
  int k0   = flat & 511;
  int mat  = colg >> 6;
  const float* W = (mat == 0) ? Wq : (mat == 1 ? Wk : Wv);
  f32x4 v = *(const f32x4*)(W + (size_t)(colg & 63) * 512 + k0);
  if (mat == 0) v *= QSC;
  int s = colg >> 4, r16 = colg & 15;
  int step = k0 >> 5, g = (k0 & 31) >> 3, jb = k0 & 7;
  __attribute__((aligned(8))) u16 b[4];
#pragma unroll
  for (int j = 0; j < 4; ++j) b[j] = h16(v[j]);
  *(uint2*)(wlin + ((size_t)(s * 16 + step) * 64 + g * 16 + r16) * 8 + jb) = *(uint2*)b;
}

// ---------------- QKV projection (unchanged from round 8) ----------------
__global__ __launch_bounds__(256, 4) void proj_kernel(const float* __restrict__ x,
                                                      const u16* __restrict__ wlin,
                                                      u16* __restrict__ ws) {
  __shared__ __attribute__((aligned(16))) u16 xl[8192];
  float* scr = (float*)xl;

  const int tid  = threadIdx.x;
  const int blk  = blockIdx.x;
  const int lane = tid & 63;
  const int ng   = tid >> 6;
  const int r16  = lane & 15;
  const int g    = lane >> 4;
  const int m0   = blk * 16;

#pragma unroll
  for (int i = 0; i < 8; ++i) {
    int f = tid * 4 + i * 1024;
    int row = f >> 9, k0 = f & 511;
    f32x4 v = *(const f32x4*)(x + (size_t)m0 * 512 + f);
    __attribute__((aligned(8))) u16 b[4];
#pragma unroll
    for (int j = 0; j < 4; ++j) b[j] = h16(v[j]);
    int ln = ((k0 & 31) >> 3) * 16 + row;
    *(uint2*)(xl + ((size_t)(k0 >> 5) * 64 + ln) * 8 + (k0 & 7)) = *(uint2*)b;
  }
  __syncthreads();

  f32x4 acc[3];
#pragma unroll
  for (int s = 0; s < 3; ++s) acc[s] = (f32x4){0.f, 0.f, 0.f, 0.f};

#pragma unroll 2
  for (int step = 0; step < 16; ++step) {
    f16x8 a = *(const f16x8*)(xl + ((size_t)step * 64 + lane) * 8);
#pragma unroll
    for (int s = 0; s < 3; ++s) {
      int sg = ng * 3 + s;
      f16x8 b = *(const f16x8*)(wlin + ((size_t)(sg * 16 + step) * 64 + lane) * 8);
      acc[s] = __builtin_amdgcn_mfma_f32_16x16x32_f16(a, b, acc[s], 0, 0, 0);
    }
  }
  __syncthreads();

#pragma unroll
  for (int s = 0; s < 3; ++s)
#pragma unroll
    for (int rr = 0; rr < 4; ++rr)
      scr[(g * 4 + rr) * 193 + ng * 48 + s * 16 + r16] = acc[s][rr];
  __syncthreads();

  u16* Ql = ws + (QL_B >> 1);
  u16* Kl = ws + (KL_B >> 1);
  u16* Vl = ws + (VL_B >> 1);
  const int batch = m0 >> 12;
  const int tile  = (m0 >> 5) & 127;
  const int half  = (m0 >> 4) & 1;

  {
    int t2 = tid & 127;
    int r  = t2 & 15, hh = (t2 >> 4) & 1, ch = t2 >> 5;
    int l31 = half * 16 + r;
    __attribute__((aligned(16))) u16 b[8];
    if (tid < 128) {
#pragma unroll
      for (int j = 0; j < 8; ++j) b[j] = h16(scr[r * 193 + 64 + ch * 16 + hh * 8 + j]);
      *(uint4*)(Kl + ((size_t)((batch * 128 + tile) * 4 + ch) * 64 + hh * 32 + l31) * 8) =
          *(uint4*)b;
    } else {
#pragma unroll
      for (int j = 0; j < 8; ++j) b[j] = h16(scr[r * 193 + ch * 16 + hh * 8 + j]);
      int qhalf = (m0 >> 5);
      *(uint4*)(Ql + ((size_t)(qhalf * 4 + ch) * 64 + hh * 32 + l31) * 8) = *(uint4*)b;
    }
  }
  {
    int z = tid & 1, l31 = (tid >> 1) & 31, hh = (tid >> 6) & 1, db = tid >> 7;
    int d = db * 32 + l31;
    __attribute__((aligned(8))) u16 b[4];
#pragma unroll
    for (int j = 0; j < 4; ++j) b[j] = h16(scr[(8 * z + 4 * hh + j) * 193 + 128 + d]);
    *(uint2*)(Vl + ((size_t)(((batch * 128 + tile) * 2 + db) * 2 + half) * 64 + hh * 32 + l31) *
                       8 + z * 4) = *(uint2*)b;
  }
}

// ---------------- flash attention: LDS-shared K/V, 2 blocks/CU ----------------
// 512 blocks (64 q-blocks x 8 kv-splits; blockIdx%8 = split). Block: 512 thr = 8 waves;
// wave w owns q rows qb*256 + w*32 (exclusive). All waves stage (2 gl16 each) 64-kv
// pairs into a 16KB double buffer; 8 barriers total; compute 2 sub-tiles per stage.
__global__ __launch_bounds__(512, 4) void attn_kernel(u16* __restrict__ ws) {
  __shared__ __attribute__((aligned(16))) u16 kvb[2][8192];  // [buf][16KB: K0 K1 V0 V1]

  const int tid  = threadIdx.x;
  const int w    = tid >> 6;
  const int lane = tid & 63;
  const int l31  = lane & 31;
  const int h    = lane >> 5;
  const int bx   = blockIdx.x;
  const int qb   = bx >> 3;     // 0..63 (256 q-rows each)
  const int sp   = bx & 7;      // kv split -> XCD
  const int bb   = qb >> 4;     // batch (16 q-blocks per batch)
  const int q0   = qb * 256 + w * 32;

  const u16* Ql = ws + (QL_B >> 1);
  const u16* Kl = ws + (KL_B >> 1);
  const u16* Vl = ws + (VL_B >> 1);

  const int qhalf = qb * 8 + w;
  f16x8 qf[4];
#pragma unroll
  for (int ch = 0; ch < 4; ++ch)
    qf[ch] = *(const f16x8*)(Ql + ((size_t)(qhalf * 4 + ch) * 64 + lane) * 8);

  f32x16 oacc[2];
#pragma unroll
  for (int db = 0; db < 2; ++db)
#pragma unroll
    for (int r = 0; r < 16; ++r) oacc[db][r] = 0.f;
  float mrun = -INFINITY, lrun = 0.f;
  const float RTHR = 11.0f;

  const int kt0 = bb * 128 + sp * 16;  // 16 tiles of 32 kv

  // stage pair p (2 tiles = 16 chunks of 1KB) into buf b; wave w does chunks 2w,2w+1
  auto stage = [&](int b, int p) {
#pragma unroll
    for (int cc = 0; cc < 2; ++cc) {
      const int c = w * 2 + cc;
      const u16* src;
      if (c < 8) {  // K: sub = c>>2, ch = c&3
        src = Kl + (size_t)(kt0 + p * 2 + (c >> 2)) * 2048 + (c & 3) * 512 + lane * 8;
      } else {      // V: sub = (c-8)>>2, q = (c-8)&3
        const int c2 = c - 8;
        src = Vl + (size_t)(kt0 + p * 2 + (c2 >> 2)) * 2048 + (c2 & 3) * 512 + lane * 8;
      }
      gl16(src, &kvb[b][c * 512]);
    }
  };

  stage(0, 0);
  __syncthreads();

#pragma unroll 1
  for (int p = 0; p < 8; ++p) {
    const int cur = p & 1;
    if (p < 7) stage(cur ^ 1, p + 1);

#pragma unroll
    for (int s = 0; s < 2; ++s) {
      // fragments from LDS (lane-linear b128, conflict-free)
      f16x8 ka[4], vp[2][2];
#pragma unroll
      for (int ch = 0; ch < 4; ++ch)
        ka[ch] = *(const f16x8*)&kvb[cur][((s << 2) + ch) * 512 + lane * 8];
#pragma unroll
      for (int db = 0; db < 2; ++db)
#pragma unroll
        for (int pp = 0; pp < 2; ++pp)
          vp[db][pp] = *(const f16x8*)&kvb[cur][(8 + (s << 2) + db * 2 + pp) * 512 + lane * 8];

      // S^T = K * Q^T
      f32x16 sac;
#pragma unroll
      for (int r = 0; r < 16; ++r) sac[r] = 0.f;
#pragma unroll
      for (int ch = 0; ch < 4; ++ch)
        sac = __builtin_amdgcn_mfma_f32_32x32x16_f16(ka[ch], qf[ch], sac, 0, 0, 0);

      // lane-local defer-max softmax
      float mt = sac[0];
#pragma unroll
      for (int r = 1; r < 16; ++r) mt = fmaxf(mt, sac[r]);
      if (__any(mt > mrun + RTHR)) {
        float mtw  = fmaxf(mt, __shfl_xor(mt, 32));
        float nm   = fmaxf(mrun, mtw);
        float corr = exp2f(mrun - nm);
        lrun *= corr;
        mrun = nm;
#pragma unroll
        for (int db = 0; db < 2; ++db)
#pragma unroll
          for (int r = 0; r < 16; ++r) oacc[db][r] *= corr;
      }
#pragma unroll
      for (int r = 0; r < 16; ++r) {
        float pv = exp2f(sac[r] - mrun);
        sac[r] = pv;
        lrun += pv;
      }

      // P -> B-fragments of 32x32x8 directly (no cross-lane ops)
      f16x4 pb[4];
#pragma unroll
      for (int c = 0; c < 4; ++c) {
        u32x2 pk;
        pk[0] = pkrtz(sac[4 * c + 0], sac[4 * c + 1]);
        pk[1] = pkrtz(sac[4 * c + 2], sac[4 * c + 3]);
        pb[c] = __builtin_bit_cast(f16x4, pk);
      }

      // O^T += V^T * P^T
#pragma unroll
      for (int db = 0; db < 2; ++db)
#pragma unroll
        for (int pp = 0; pp < 2; ++pp) {
          f16x4 vlo = __builtin_shufflevector(vp[db][pp], vp[db][pp], 0, 1, 2, 3);
          f16x4 vhi = __builtin_shufflevector(vp[db][pp], vp[db][pp], 4, 5, 6, 7);
          oacc[db] = __builtin_amdgcn_mfma_f32_32x32x8f16(vlo, pb[2 * pp], oacc[db], 0, 0, 0);
          oacc[db] = __builtin_amdgcn_mfma_f32_32x32x8f16(vhi, pb[2 * pp + 1], oacc[db], 0, 0, 0);
        }
    }
    __syncthreads();  // drains staged loads; guards buffer reuse
  }

  lrun += __shfl_xor(lrun, 32);

  // epilogue: unnormalized partial O + (m,l); q-rows exclusive per wave
  float* Op = (float*)((char*)ws + PART_B) + (size_t)sp * MTOT * 64;
#pragma unroll
  for (int db = 0; db < 2; ++db)
#pragma unroll
    for (int r = 0; r < 16; ++r) {
      int d = db * 32 + (r & 3) + 8 * (r >> 2) + 4 * h;
      Op[(size_t)(q0 + l31) * 64 + d] = oacc[db][r];
    }
  if (h == 0) {
    float* Mm = (float*)((char*)ws + ML_B);
    float* Ll = Mm + 8 * MTOT;
    Mm[(size_t)sp * MTOT + q0 + l31] = mrun;
    Ll[(size_t)sp * MTOT + q0 + l31] = lrun;
  }
}

// ---------------- merge the 8 kv-splits ----------------
__global__ __launch_bounds__(256) void merge_kernel(const u16* __restrict__ ws,
                                                    float* __restrict__ out) {
  int gid = blockIdx.x * 256 + threadIdx.x;  // 65536 threads
  int row = gid >> 2, dg = gid & 3;
  const float* Mm = (const float*)((const char*)ws + ML_B);
  const float* Ll = Mm + 8 * MTOT;
  float mv[8];
  float mg = -INFINITY;
#pragma unroll
  for (int i = 0; i < 8; ++i) {
    mv[i] = Mm[(size_t)i * MTOT + row];
    mg = fmaxf(mg, mv[i]);
  }
  float den = 0.f, wv[8];
#pragma unroll
  for (int i = 0; i < 8; ++i) {
    wv[i] = exp2f(mv[i] - mg);
    den += wv[i] * Ll[(size_t)i * MTOT + row];
  }
  f32x4 acc[4];
#pragma unroll
  for (int m = 0; m < 4; ++m) acc[m] = (f32x4){0.f, 0.f, 0.f, 0.f};
  const float* Op = (const float*)((const char*)ws + PART_B);
#pragma unroll
  for (int i = 0; i < 8; ++i)
#pragma unroll
    for (int m = 0; m < 4; ++m) {
      f32x4 t = *(const f32x4*)(Op + ((size_t)i * MTOT + row) * 64 + dg * 16 + m * 4);
      acc[m] += wv[i] * t;
    }
  float inv = 1.f / den;
#pragma unroll
  for (int m = 0; m < 4; ++m) {
    f32x4 r = acc[m] * inv;
    *(f32x4*)(out + (size_t)row * 64 + dg * 16 + m * 4) = r;
  }
}

extern "C" void kernel_launch(void* const* d_in, const int* in_sizes, int n_in,
                              void* d_out, int out_size, void* d_ws, size_t ws_size,
                              hipStream_t stream) {
  const float* x  = (const float*)d_in[0];
  const float* Wq = (const float*)d_in[1];
  const float* Wk = (const float*)d_in[2];
  const float* Wv = (const float*)d_in[3];
  u16* ws = (u16*)d_ws;
  (void)in_sizes; (void)n_in; (void)out_size; (void)ws_size;

  wconv_kernel<<<96, 256, 0, stream>>>(Wq, Wk, Wv, ws + (WL_B >> 1));
  proj_kernel<<<1024, 256, 0, stream>>>(x, ws + (WL_B >> 1), ws);
  attn_kernel<<<512, 512, 0, stream>>>(ws);
  merge_kernel<<<256, 256, 0, stream>>>(ws, (float*)d_out);
}